// Round 9
// baseline (391.531 us; speedup 1.0000x reference)
//
#include <hip/hip_runtime.h>
#include <hip/hip_fp16.h>
#include <math.h>

#define Bb 64
#define Nn 1000
#define Gg 500
#define Hh 256
#define GP 512
#define NP 1024

// float offsets into d_ws (total 42,762,240 floats = 171 MB)
#define WS_MP   0u           // [B][H] fp32 column sums (zeroed each launch)
#define WS_QG   16384u       // [B][H] fp32 q_graph
#define WS_BM   32768u       // u16 [B][GP][64] visited bitmask
#define WS_WCH  1081344u     // u16 [256][512] Wcat hi
#define WS_WCL  1146880u     // u16 [256][512] Wcat lo
#define WS_EH   1212416u     // u16 [B][N][H] emb hi
#define WS_EL   9404416u     // u16 [B][N][H] emb lo
#define WS_TH   17596416u    // u16 [B][H][NP] embT hi (dead after k_pool)
#define WS_PH   25985024u    // u16 [B][GP][H] pooled hi (dead after k_finalq)
#define WS_PL2  30179328u    // u16 [B][GP][H] pooled lo (dead after k_finalq)
#define WS_FH   17596416u    // u16 [B][GP][H] fq hi (overlays embT TH)
#define WS_FL   21790720u    // u16 [B][GP][H] fq lo (overlays TH 2nd half)
#define WS_PO   25985024u    // u16 [B][500][1024] unnorm p (overlays PH+PL2+...)
#define WS_RS   42369024u    // [B][GP] fp32 row sums (exclusive, zeroed)

typedef __attribute__((ext_vector_type(8))) short bf16x8;
typedef __attribute__((ext_vector_type(8))) short short8;
typedef __attribute__((ext_vector_type(4))) float f32x4;
typedef __attribute__((ext_vector_type(4))) unsigned short u16x4;

#define MFMA(a,b,c) __builtin_amdgcn_mfma_f32_16x16x32_bf16(a,b,c,0,0,0)
// swizzled LDS offset (shorts): 64-short rows, 8 chunks of 8 bf16 (16B)
#define SW(row, chunk) (((row) << 6) + ((((chunk) ^ ((row) & 7))) << 3))

// round-to-nearest bf16 split: hi = RN(v), lo = RN(v - hi)
__device__ __forceinline__ unsigned short bf16rn(float v) {
  unsigned bits = __float_as_uint(v);
  unsigned r = bits + 0x7FFFu + ((bits >> 16) & 1u);
  return (unsigned short)(r >> 16);
}
__device__ __forceinline__ void split1(float v, unsigned short& hi, unsigned short& lo) {
  hi = bf16rn(v);
  float hf = __uint_as_float(((unsigned)hi) << 16);
  lo = bf16rn(v - hf);
}

// ---------------- zero MP + RS: grid(192), block(256) ----------------
__global__ __launch_bounds__(256) void k_zero(float* __restrict__ ws) {
  int bid = blockIdx.x, t = threadIdx.x;
  if (bid < 64) ws[WS_MP + bid * 256 + t] = 0.f;
  else          ws[WS_RS + (bid - 64) * 256 + t] = 0.f;
}

// ---------------- prep: emb -> eh/el + th + column sums ----------------
// grid(nt=16, ht=4, b=64), block(256)
__global__ __launch_bounds__(256) void k_prep(const float* __restrict__ emb,
                                              float* __restrict__ ws) {
  __shared__ float tile[64][65];
  __shared__ float csumL[256];
  int nt = blockIdx.x, ht = blockIdx.y, b = blockIdx.z;
  int t = threadIdx.x, c = t & 63, w = t >> 6;
  int n0 = nt * 64, h0 = ht * 64;
  unsigned short* eh = (unsigned short*)(ws + WS_EH);
  unsigned short* el = (unsigned short*)(ws + WS_EL);
  unsigned short* th = (unsigned short*)(ws + WS_TH);
  float csum = 0.f;
#pragma unroll
  for (int rr = 0; rr < 16; ++rr) {
    int r = w * 16 + rr;
    int n = n0 + r;
    float v = 0.f;
    if (n < Nn) {
      size_t idx = ((size_t)(b * Nn + n)) * Hh + h0 + c;
      v = emb[idx];
      unsigned short hi, lo;
      split1(v, hi, lo);
      eh[idx] = hi; el[idx] = lo;
    }
    tile[r][c] = v;
    csum += v;
  }
  __syncthreads();
  {
    int h_l = t >> 2, nseg = t & 3;
    short8 h8a, h8b;
#pragma unroll
    for (int i = 0; i < 16; ++i) {
      float v = tile[nseg * 16 + i][h_l];
      unsigned short hi = bf16rn(v);
      if (i < 8) h8a[i] = (short)hi;
      else       h8b[i-8] = (short)hi;
    }
    size_t base = ((size_t)(b * Hh + h0 + h_l)) * NP + n0 + nseg * 16;
    *(short8*)(th + base) = h8a; *(short8*)(th + base + 8) = h8b;
  }
  __syncthreads();
  csumL[t] = csum;
  __syncthreads();
  if (t < 64) {
    float s = csumL[t] + csumL[t+64] + csumL[t+128] + csumL[t+192];
    atomicAdd(ws + WS_MP + b * Hh + h0 + t, s);
  }
}

// ---------------- q_graph: grid(B), block(256) ----------------
__global__ __launch_bounds__(256) void k_qgraph(const float* __restrict__ Wg,
                                                float* __restrict__ ws) {
  __shared__ float mean[Hh];
  int b = blockIdx.x, t = threadIdx.x;
  mean[t] = ws[WS_MP + b*Hh + t] * (1.0f/Nn);
  __syncthreads();
  const float4* wrow = (const float4*)(Wg + (size_t)t * Hh);
  float acc = 0.f;
#pragma unroll
  for (int h4 = 0; h4 < Hh/4; ++h4) {
    float4 w = wrow[h4];
    acc += mean[h4*4]*w.x + mean[h4*4+1]*w.y + mean[h4*4+2]*w.z + mean[h4*4+3]*w.w;
  }
  ws[WS_QG + b*Hh + t] = acc;
}

// ---------------- Wcat bf16 hi/lo: grid(256), block(256) ----------------
__global__ __launch_bounds__(256) void k_wcat(const float* __restrict__ Wf,
                                              const float* __restrict__ Wl,
                                              const float* __restrict__ Wv,
                                              float* __restrict__ ws) {
  int o = blockIdx.x, k = threadIdx.x;
  unsigned short* wh = (unsigned short*)(ws + WS_WCH);
  unsigned short* wl = (unsigned short*)(ws + WS_WCL);
  unsigned short hi, lo;
  float v0 = Wv[o*Hh + k];
  split1(v0, hi, lo);
  wh[o*512 + k] = hi; wl[o*512 + k] = lo;
  float v1 = Wl[o*Hh + k] + Wf[o*Hh + k];
  split1(v1, hi, lo);
  wh[o*512 + 256 + k] = hi; wl[o*512 + 256 + k] = lo;
}

// ---------------- bitmask: gm -> 1 bit per (b,g,n): grid(B*GP/4), block(256) ----
__global__ __launch_bounds__(256) void k_bm(const float* __restrict__ gm,
                                            float* __restrict__ ws) {
  int w = threadIdx.x >> 6, l = threadIdx.x & 63;
  int row = blockIdx.x * 4 + w;          // b*GP + g
  int b = row >> 9, g = row & 511;
  unsigned long long* dst = (unsigned long long*)((unsigned short*)(ws + WS_BM) + (size_t)row * 64);
  if (g < Gg) {
    const float* src = gm + ((size_t)b * Gg + g) * Nn;
#pragma unroll
    for (int i = 0; i < 16; ++i) {
      int n = i * 64 + l;
      bool bit = (n < Nn) ? (src[n] < -1e30f) : false;
      unsigned long long m = __ballot(bit);
      if (l == i) dst[i] = m;
    }
  } else {
    if (l < 16) dst[l] = 0ull;
  }
}

// ---------------- pool GEMM: pooled[g][h] = (1/N) mask @ emb_hi ----------------
// grid(ht=2, gt=4, b=64), block(256)=2x2 waves, wave tile 64h x 64g, BK=64
__global__ __launch_bounds__(256, 2) void k_pool(float* __restrict__ ws) {
  __shared__ __align__(16) unsigned short sTH[128*64];
  int ht = blockIdx.x, gt = blockIdx.y, b = blockIdx.z;
  int t = threadIdx.x, w = t >> 6, lane = t & 63;
  int wh = w >> 1, wg = w & 1, l15 = lane & 15, lk = lane >> 4;
  const unsigned short* th = (const unsigned short*)(ws + WS_TH);
  const unsigned short* bmp = (const unsigned short*)(ws + WS_BM);
  unsigned short* ph = (unsigned short*)(ws + WS_PH);
  unsigned short* pl = (unsigned short*)(ws + WS_PL2);
  int h0 = ht*128, g0 = gt*128;
  f32x4 acc[4][4] = {};
  const unsigned short* brow[4];
#pragma unroll
  for (int fn = 0; fn < 4; ++fn) {
    int g = g0 + wg*64 + fn*16 + l15; if (g > Gg-1) g = Gg-1;
    brow[fn] = bmp + ((size_t)(b*GP + g)) * 64;
  }
  int bitoff = (lk & 1) * 8;
  int srow = t >> 1, sc0 = (t & 1) * 4;
  size_t sbase = ((size_t)(b*Hh + h0 + srow)) * NP;
  for (int st = 0; st < 16; ++st) {
    int k0 = st * 64;
#pragma unroll
    for (int i = 0; i < 4; ++i) {
      int cc = sc0 + i;
      *(bf16x8*)&sTH[SW(srow, cc)] = *(const bf16x8*)(th + sbase + k0 + cc*8);
    }
    __syncthreads();
#pragma unroll
    for (int kk = 0; kk < 64; kk += 32) {
      bf16x8 ah[4], bmf[4];
#pragma unroll
      for (int fm = 0; fm < 4; ++fm)
        ah[fm] = *(const bf16x8*)&sTH[SW(wh*64 + fm*16 + l15, (kk>>3) + lk)];
#pragma unroll
      for (int fn = 0; fn < 4; ++fn) {
        unsigned c = brow[fn][((k0 + kk) >> 4) + (lk >> 1)];
#pragma unroll
        for (int i = 0; i < 8; ++i)
          bmf[fn][i] = ((c >> (bitoff + i)) & 1) ? (short)0x3F80 : (short)0;
      }
#pragma unroll
      for (int fm = 0; fm < 4; ++fm)
#pragma unroll
        for (int fn = 0; fn < 4; ++fn)
          acc[fm][fn] = MFMA(ah[fm], bmf[fn], acc[fm][fn]);
    }
    __syncthreads();
  }
#pragma unroll
  for (int fm = 0; fm < 4; ++fm)
#pragma unroll
    for (int fn = 0; fn < 4; ++fn) {
      int h = h0 + wh*64 + fm*16 + lk*4;
      int g = g0 + wg*64 + fn*16 + l15;
      u16x4 vh, vl;
#pragma unroll
      for (int j = 0; j < 4; ++j) {
        unsigned short hi, lo;
        split1(acc[fm][fn][j] * (1.0f/Nn), hi, lo);
        vh[j] = hi; vl[j] = lo;
      }
      size_t idx = ((size_t)(b*GP + g)) * Hh + h;
      *(u16x4*)(ph + idx) = vh;
      *(u16x4*)(pl + idx) = vl;
    }
}

// ---------------- finalq GEMM: fq[g][o] = Wcat@[pooled|lastE]^T + qg ----------
// grid(ot=2, gt=4, b=64), block(256)=2x2 waves, wave tile 64o x 64g, K=512, BK=64
__global__ __launch_bounds__(256, 2) void k_finalq(const int* __restrict__ last_node,
                                                   float* __restrict__ ws) {
  __shared__ __align__(16) unsigned short sAH[128*64], sAL[128*64],
                                          sBH[128*64], sBL[128*64];
  __shared__ int lL[128];
  int ot = blockIdx.x, gt = blockIdx.y, b = blockIdx.z;
  int t = threadIdx.x, w = t >> 6, lane = t & 63;
  int wo = w >> 1, wg = w & 1, l15 = lane & 15, lk = lane >> 4;
  const unsigned short* wch = (const unsigned short*)(ws + WS_WCH);
  const unsigned short* wcl = (const unsigned short*)(ws + WS_WCL);
  const unsigned short* ph = (const unsigned short*)(ws + WS_PH);
  const unsigned short* pl = (const unsigned short*)(ws + WS_PL2);
  const unsigned short* eh = (const unsigned short*)(ws + WS_EH);
  const unsigned short* el = (const unsigned short*)(ws + WS_EL);
  unsigned short* fh = (unsigned short*)(ws + WS_FH);
  unsigned short* fl = (unsigned short*)(ws + WS_FL);
  int o0 = ot*128, g0 = gt*128;
  if (t < 128) lL[t] = last_node[b*Gg + ((g0 + t) < Gg ? (g0 + t) : Gg-1)];
  __syncthreads();
  f32x4 acc[4][4] = {};
  int srow = t >> 1, sc0 = (t & 1) * 4;
  size_t abase = ((size_t)(o0 + srow)) * 512;
  size_t pbase = ((size_t)(b*GP + g0 + srow)) * Hh;
  size_t lbase = ((size_t)(b*Nn + lL[srow])) * Hh;
  for (int st = 0; st < 8; ++st) {
    int k0 = st * 64;
#pragma unroll
    for (int i = 0; i < 4; ++i) {
      int cc = sc0 + i;
      int d = SW(srow, cc);
      *(bf16x8*)&sAH[d] = *(const bf16x8*)(wch + abase + k0 + cc*8);
      *(bf16x8*)&sAL[d] = *(const bf16x8*)(wcl + abase + k0 + cc*8);
      if (k0 < 256) {
        *(bf16x8*)&sBH[d] = *(const bf16x8*)(ph + pbase + k0 + cc*8);
        *(bf16x8*)&sBL[d] = *(const bf16x8*)(pl + pbase + k0 + cc*8);
      } else {
        *(bf16x8*)&sBH[d] = *(const bf16x8*)(eh + lbase + (k0 - 256) + cc*8);
        *(bf16x8*)&sBL[d] = *(const bf16x8*)(el + lbase + (k0 - 256) + cc*8);
      }
    }
    __syncthreads();
#pragma unroll
    for (int kk = 0; kk < 64; kk += 32) {
      bf16x8 ahi[4], alo[4], bhi[4], blo[4];
#pragma unroll
      for (int fm = 0; fm < 4; ++fm) {
        int d = SW(wo*64 + fm*16 + l15, (kk>>3) + lk);
        ahi[fm] = *(const bf16x8*)&sAH[d];
        alo[fm] = *(const bf16x8*)&sAL[d];
      }
#pragma unroll
      for (int fn = 0; fn < 4; ++fn) {
        int d = SW(wg*64 + fn*16 + l15, (kk>>3) + lk);
        bhi[fn] = *(const bf16x8*)&sBH[d];
        blo[fn] = *(const bf16x8*)&sBL[d];
      }
#pragma unroll
      for (int fm = 0; fm < 4; ++fm)
#pragma unroll
        for (int fn = 0; fn < 4; ++fn) {
          acc[fm][fn] = MFMA(ahi[fm], bhi[fn], acc[fm][fn]);
          acc[fm][fn] = MFMA(ahi[fm], blo[fn], acc[fm][fn]);
          acc[fm][fn] = MFMA(alo[fm], bhi[fn], acc[fm][fn]);
        }
    }
    __syncthreads();
  }
#pragma unroll
  for (int fm = 0; fm < 4; ++fm) {
    int o = o0 + wo*64 + fm*16 + lk*4;
    float4 qv = *(const float4*)(ws + WS_QG + b*Hh + o);
    float q4[4] = {qv.x, qv.y, qv.z, qv.w};
#pragma unroll
    for (int fn = 0; fn < 4; ++fn) {
      int g = g0 + wg*64 + fn*16 + l15;
      u16x4 vh, vl;
#pragma unroll
      for (int j = 0; j < 4; ++j) {
        unsigned short hi, lo;
        split1(acc[fm][fn][j] + q4[j], hi, lo);
        vh[j] = hi; vl[j] = lo;
      }
      size_t idx = ((size_t)(b*GP + g)) * Hh + o;
      *(u16x4*)(fh + idx) = vh;
      *(u16x4*)(fl + idx) = vl;
    }
  }
}

// ---------------- score GEMM + fp16 p + rowsum atomics ----------------
// grid(nt=8, gt=4, b=64), block(256)=2x2 waves, wave tile 64n x 64g, K=256, BK=64
__global__ __launch_bounds__(256, 2) void k_score(const float* __restrict__ dists,
                                                  const int* __restrict__ last_node,
                                                  float* __restrict__ ws) {
  __shared__ __align__(16) unsigned short sEH[128*64], sEL[128*64],
                                          sFH[128*64], sFL[128*64];
  __shared__ int lL[128];
  int nt = blockIdx.x, gt = blockIdx.y, b = blockIdx.z;
  int t = threadIdx.x, w = t >> 6, lane = t & 63;
  int wn = w >> 1, wg = w & 1, l15 = lane & 15, lk = lane >> 4;
  const unsigned short* eh = (const unsigned short*)(ws + WS_EH);
  const unsigned short* el = (const unsigned short*)(ws + WS_EL);
  const unsigned short* fh = (const unsigned short*)(ws + WS_FH);
  const unsigned short* fl = (const unsigned short*)(ws + WS_FL);
  const unsigned short* bmp = (const unsigned short*)(ws + WS_BM);
  unsigned short* po = (unsigned short*)(ws + WS_PO);
  float* rs = ws + WS_RS;
  int n0 = nt*128, g0 = gt*128;
  if (t < 128) lL[t] = last_node[b*Gg + ((g0 + t) < Gg ? (g0 + t) : Gg-1)];
  __syncthreads();
  f32x4 acc[4][4] = {};
  int srow = t >> 1, sc0 = (t & 1) * 4;
  int nr = n0 + srow; if (nr > Nn-1) nr = Nn-1;
  size_t ebase = ((size_t)(b*Nn + nr)) * Hh;
  size_t fbase = ((size_t)(b*GP + g0 + srow)) * Hh;
  for (int st = 0; st < 4; ++st) {
    int k0 = st * 64;
#pragma unroll
    for (int i = 0; i < 4; ++i) {
      int cc = sc0 + i;
      int d = SW(srow, cc);
      *(bf16x8*)&sEH[d] = *(const bf16x8*)(eh + ebase + k0 + cc*8);
      *(bf16x8*)&sEL[d] = *(const bf16x8*)(el + ebase + k0 + cc*8);
      *(bf16x8*)&sFH[d] = *(const bf16x8*)(fh + fbase + k0 + cc*8);
      *(bf16x8*)&sFL[d] = *(const bf16x8*)(fl + fbase + k0 + cc*8);
    }
    __syncthreads();
#pragma unroll
    for (int kk = 0; kk < 64; kk += 32) {
      bf16x8 ahi[4], alo[4], bhi[4], blo[4];
#pragma unroll
      for (int fm = 0; fm < 4; ++fm) {
        int d = SW(wn*64 + fm*16 + l15, (kk>>3) + lk);
        ahi[fm] = *(const bf16x8*)&sEH[d];
        alo[fm] = *(const bf16x8*)&sEL[d];
      }
#pragma unroll
      for (int fn = 0; fn < 4; ++fn) {
        int d = SW(wg*64 + fn*16 + l15, (kk>>3) + lk);
        bhi[fn] = *(const bf16x8*)&sFH[d];
        blo[fn] = *(const bf16x8*)&sFL[d];
      }
#pragma unroll
      for (int fm = 0; fm < 4; ++fm)
#pragma unroll
        for (int fn = 0; fn < 4; ++fn) {
          acc[fm][fn] = MFMA(ahi[fm], bhi[fn], acc[fm][fn]);
          acc[fm][fn] = MFMA(ahi[fm], blo[fn], acc[fm][fn]);
          acc[fm][fn] = MFMA(alo[fm], bhi[fn], acc[fm][fn]);
        }
    }
    __syncthreads();
  }
  const float c2 = 0.70710678118654752f;
  float rsum[4] = {0.f, 0.f, 0.f, 0.f};
#pragma unroll
  for (int fn = 0; fn < 4; ++fn) {
    int gl = wg*64 + fn*16 + l15;
    int g = g0 + gl;
    if (g < Gg) {
      int L = lL[gl];
      const float* drow = dists + ((size_t)(b*Nn + L)) * Nn;
      const unsigned short* bmr = bmp + ((size_t)(b*GP + g)) * 64;
      unsigned short* prow = po + ((size_t)(b*Gg + g)) * 1024;
#pragma unroll
      for (int fm = 0; fm < 4; ++fm) {
        int n = n0 + wn*64 + fm*16 + lk*4;
        if (n < Nn) {
          float4 d4 = *(const float4*)(drow + n);
          unsigned cb = bmr[n >> 4];
          int bo = n & 15;
          float dd[4] = {d4.x, d4.y, d4.z, d4.w};
          unsigned short h4[4];
#pragma unroll
          for (int j = 0; j < 4; ++j) {
            // p = exp(10*tanh(s) - 10), exp2-domain, rcp-approx division
            float s = fmaf(acc[fm][fn][j], 0.0625f, -dd[j] * c2);
            float e = __expf(-2.0f * fabsf(s));
            float r = __builtin_amdgcn_rcpf(1.0f + e);
            float m = fmaf(-20.0f, e * r, 10.0f);   // = 10*tanh(|s|)
            float parg = copysignf(m, s) - 10.0f;
            float p = ((cb >> (bo + j)) & 1) ? 0.f : __expf(parg);
            rsum[fn] += p;
            h4[j] = __half_as_ushort(__float2half(p));
          }
          uint2 u = { (unsigned)h4[0] | ((unsigned)h4[1] << 16),
                      (unsigned)h4[2] | ((unsigned)h4[3] << 16) };
          *(uint2*)(prow + n) = u;
        }
      }
    }
  }
#pragma unroll
  for (int fn = 0; fn < 4; ++fn) {
    rsum[fn] += __shfl_xor(rsum[fn], 16);
    rsum[fn] += __shfl_xor(rsum[fn], 32);
    int g = g0 + wg*64 + fn*16 + l15;
    if (lk == 0 && g < Gg) atomicAdd(rs + b*GP + g, rsum[fn]);
  }
}

// ---------------- normalize: out[g][n] = fp16 p * (1/rs): grid(31250) ---------
__global__ __launch_bounds__(256) void k_norm(const float* __restrict__ ws,
                                              float* __restrict__ out) {
  int idx = blockIdx.x * 256 + threadIdx.x;   // float4 index, < 8,000,000
  int bg = idx / 250;                         // b*Gg + g
  int n = (idx - bg * 250) * 4;
  int b = bg / Gg, g = bg - b * Gg;
  const unsigned short* po = (const unsigned short*)(ws + WS_PO);
  float inv = 1.0f / ws[WS_RS + b*GP + g];
  uint2 u = *(const uint2*)(po + (size_t)bg * 1024 + n);
  float4 o4;
  o4.x = __half2float(__ushort_as_half((unsigned short)(u.x & 0xFFFF))) * inv;
  o4.y = __half2float(__ushort_as_half((unsigned short)(u.x >> 16))) * inv;
  o4.z = __half2float(__ushort_as_half((unsigned short)(u.y & 0xFFFF))) * inv;
  o4.w = __half2float(__ushort_as_half((unsigned short)(u.y >> 16))) * inv;
  *(float4*)(out + (size_t)bg * Nn + n) = o4;
}

extern "C" void kernel_launch(void* const* d_in, const int* in_sizes, int n_in,
                              void* d_out, int out_size, void* d_ws, size_t ws_size,
                              hipStream_t stream) {
  const float* emb       = (const float*)d_in[0];
  const float* dists     = (const float*)d_in[1];
  const int*   last_node = (const int*)d_in[2];
  const float* gm        = (const float*)d_in[3];
  const float* Wg        = (const float*)d_in[4];
  const float* Wf        = (const float*)d_in[5];
  const float* Wl        = (const float*)d_in[6];
  const float* Wv        = (const float*)d_in[7];
  float* out = (float*)d_out;
  float* ws  = (float*)d_ws;

  hipLaunchKernelGGL(k_zero,   dim3(192),       dim3(256), 0, stream, ws);
  hipLaunchKernelGGL(k_prep,   dim3(16,4,Bb),   dim3(256), 0, stream, emb, ws);
  hipLaunchKernelGGL(k_qgraph, dim3(Bb),        dim3(256), 0, stream, Wg, ws);
  hipLaunchKernelGGL(k_wcat,   dim3(256),       dim3(256), 0, stream, Wf, Wl, Wv, ws);
  hipLaunchKernelGGL(k_bm,     dim3(Bb*GP/4),   dim3(256), 0, stream, gm, ws);
  hipLaunchKernelGGL(k_pool,   dim3(2,4,Bb),    dim3(256), 0, stream, ws);
  hipLaunchKernelGGL(k_finalq, dim3(2,4,Bb),    dim3(256), 0, stream, last_node, ws);
  hipLaunchKernelGGL(k_score,  dim3(8,4,Bb),    dim3(256), 0, stream, dists, last_node, ws);
  hipLaunchKernelGGL(k_norm,   dim3(31250),     dim3(256), 0, stream, ws, out);
}

// Round 10
// 326.868 us; speedup vs baseline: 1.1978x; 1.1978x over previous
//
#include <hip/hip_runtime.h>
#include <hip/hip_fp16.h>
#include <math.h>

#define Bb 64
#define Nn 1000
#define Gg 500
#define Hh 256
#define GP 512
#define NP 1024

// float offsets into d_ws (total 38.3M floats = 153 MB)
#define WS_MP   0u           // [B][H] fp32 column sums (zeroed each launch)
#define WS_QG   16384u       // [B][H] fp32 q_graph
#define WS_RS   32768u       // [B][GP] fp32 row sums (zeroed)
#define WS_BM   65536u       // u16 [B][GP][64] visited bitmask
#define WS_WC16 1114112u     // u16 [256][512] Wcat fp16
#define WS_E16  1179648u     // u16 [B][N][H] emb fp16 row-major
#define WS_T16  9371648u     // u16 [B][H][NP] embT fp16 (dead after k_pool)
#define WS_P16  17760256u    // u16 [B][GP][H] pooled fp16 (dead after k_finalq)
#define WS_F16  WS_T16       // u16 [B][GP][H] fq fp16 (overlays T16)
#define WS_PO   21954560u    // u16 [B][500][1024] unnorm p fp16

typedef __attribute__((ext_vector_type(8))) short short8;
typedef __attribute__((ext_vector_type(8))) _Float16 f16x8;
typedef __attribute__((ext_vector_type(4))) float f32x4;
typedef __attribute__((ext_vector_type(4))) unsigned short u16x4;

#define MFMAH(a,b,c) __builtin_amdgcn_mfma_f32_16x16x32_f16(a,b,c,0,0,0)
// swizzled LDS offset (shorts): 64-short rows, 8 chunks of 8 halves (16B)
#define SW(row, chunk) (((row) << 6) + ((((chunk) ^ ((row) & 7))) << 3))

__device__ __forceinline__ unsigned short f16b(float v) {
  return __half_as_ushort(__float2half(v));
}

// ---------------- zero MP + RS: grid(192), block(256) ----------------
__global__ __launch_bounds__(256) void k_zero(float* __restrict__ ws) {
  int bid = blockIdx.x, t = threadIdx.x;
  if (bid < 64) ws[WS_MP + bid * 256 + t] = 0.f;
  else          ws[WS_RS + (bid - 64) * 256 + t] = 0.f;
}

// ---------------- prep: emb -> e16 + t16 + column sums ----------------
// grid(nt=16, ht=4, b=64), block(256)
__global__ __launch_bounds__(256) void k_prep(const float* __restrict__ emb,
                                              float* __restrict__ ws) {
  __shared__ float tile[64][65];
  __shared__ float csumL[256];
  int nt = blockIdx.x, ht = blockIdx.y, b = blockIdx.z;
  int t = threadIdx.x, c = t & 63, w = t >> 6;
  int n0 = nt * 64, h0 = ht * 64;
  unsigned short* e16 = (unsigned short*)(ws + WS_E16);
  unsigned short* t16 = (unsigned short*)(ws + WS_T16);
  float csum = 0.f;
#pragma unroll
  for (int rr = 0; rr < 16; ++rr) {
    int r = w * 16 + rr;
    int n = n0 + r;
    float v = 0.f;
    if (n < Nn) {
      size_t idx = ((size_t)(b * Nn + n)) * Hh + h0 + c;
      v = emb[idx];
      e16[idx] = f16b(v);
    }
    tile[r][c] = v;
    csum += v;
  }
  __syncthreads();
  {
    int h_l = t >> 2, nseg = t & 3;
    short8 h8a, h8b;
#pragma unroll
    for (int i = 0; i < 16; ++i) {
      float v = tile[nseg * 16 + i][h_l];
      unsigned short hv = f16b(v);
      if (i < 8) h8a[i] = (short)hv;
      else       h8b[i-8] = (short)hv;
    }
    size_t base = ((size_t)(b * Hh + h0 + h_l)) * NP + n0 + nseg * 16;
    *(short8*)(t16 + base) = h8a; *(short8*)(t16 + base + 8) = h8b;
  }
  __syncthreads();
  csumL[t] = csum;
  __syncthreads();
  if (t < 64) {
    float s = csumL[t] + csumL[t+64] + csumL[t+128] + csumL[t+192];
    atomicAdd(ws + WS_MP + b * Hh + h0 + t, s);
  }
}

// ---------------- q_graph: grid(B), block(256) ----------------
__global__ __launch_bounds__(256) void k_qgraph(const float* __restrict__ Wg,
                                                float* __restrict__ ws) {
  __shared__ float mean[Hh];
  int b = blockIdx.x, t = threadIdx.x;
  mean[t] = ws[WS_MP + b*Hh + t] * (1.0f/Nn);
  __syncthreads();
  const float4* wrow = (const float4*)(Wg + (size_t)t * Hh);
  float acc = 0.f;
#pragma unroll
  for (int h4 = 0; h4 < Hh/4; ++h4) {
    float4 w = wrow[h4];
    acc += mean[h4*4]*w.x + mean[h4*4+1]*w.y + mean[h4*4+2]*w.z + mean[h4*4+3]*w.w;
  }
  ws[WS_QG + b*Hh + t] = acc;
}

// ---------------- Wcat fp16: grid(256), block(256) ----------------
__global__ __launch_bounds__(256) void k_wcat(const float* __restrict__ Wf,
                                              const float* __restrict__ Wl,
                                              const float* __restrict__ Wv,
                                              float* __restrict__ ws) {
  int o = blockIdx.x, k = threadIdx.x;
  unsigned short* wc = (unsigned short*)(ws + WS_WC16);
  wc[o*512 + k]       = f16b(Wv[o*Hh + k]);
  wc[o*512 + 256 + k] = f16b(Wl[o*Hh + k] + Wf[o*Hh + k]);
}

// ---------------- bitmask: gm -> 1 bit per (b,g,n): grid(B*GP/4), block(256) ----
__global__ __launch_bounds__(256) void k_bm(const float* __restrict__ gm,
                                            float* __restrict__ ws) {
  int w = threadIdx.x >> 6, l = threadIdx.x & 63;
  int row = blockIdx.x * 4 + w;          // b*GP + g
  int b = row >> 9, g = row & 511;
  unsigned long long* dst = (unsigned long long*)((unsigned short*)(ws + WS_BM) + (size_t)row * 64);
  if (g < Gg) {
    const float* src = gm + ((size_t)b * Gg + g) * Nn;
#pragma unroll
    for (int i = 0; i < 16; ++i) {
      int n = i * 64 + l;
      bool bit = (n < Nn) ? (src[n] < -1e30f) : false;
      unsigned long long m = __ballot(bit);
      if (l == i) dst[i] = m;
    }
  } else {
    if (l < 16) dst[l] = 0ull;
  }
}

// ---------------- pool GEMM: pooled[g][h] = (1/N) mask @ emb ----------------
// grid(ht=2, gt=4, b=64), block(256)=2x2 waves, wave tile 64h x 64g, BK=64
__global__ __launch_bounds__(256, 2) void k_pool(float* __restrict__ ws) {
  __shared__ __align__(16) unsigned short sT[128*64];
  int ht = blockIdx.x, gt = blockIdx.y, b = blockIdx.z;
  int t = threadIdx.x, w = t >> 6, lane = t & 63;
  int wh = w >> 1, wg = w & 1, l15 = lane & 15, lk = lane >> 4;
  const unsigned short* t16 = (const unsigned short*)(ws + WS_T16);
  const unsigned short* bmp = (const unsigned short*)(ws + WS_BM);
  unsigned short* p16 = (unsigned short*)(ws + WS_P16);
  int h0 = ht*128, g0 = gt*128;
  f32x4 acc[4][4] = {};
  const unsigned short* brow[4];
#pragma unroll
  for (int fn = 0; fn < 4; ++fn) {
    int g = g0 + wg*64 + fn*16 + l15; if (g > Gg-1) g = Gg-1;
    brow[fn] = bmp + ((size_t)(b*GP + g)) * 64;
  }
  int bitoff = (lk & 1) * 8;
  int srow = t >> 1, sc0 = (t & 1) * 4;
  size_t sbase = ((size_t)(b*Hh + h0 + srow)) * NP;
  for (int st = 0; st < 16; ++st) {
    int k0 = st * 64;
#pragma unroll
    for (int i = 0; i < 4; ++i) {
      int cc = sc0 + i;
      *(short8*)&sT[SW(srow, cc)] = *(const short8*)(t16 + sbase + k0 + cc*8);
    }
    __syncthreads();
#pragma unroll
    for (int kk = 0; kk < 64; kk += 32) {
      f16x8 ah[4], bmf[4];
#pragma unroll
      for (int fm = 0; fm < 4; ++fm)
        ah[fm] = *(const f16x8*)&sT[SW(wh*64 + fm*16 + l15, (kk>>3) + lk)];
#pragma unroll
      for (int fn = 0; fn < 4; ++fn) {
        unsigned c = brow[fn][((k0 + kk) >> 4) + (lk >> 1)];
        short8 bs;
#pragma unroll
        for (int i = 0; i < 8; ++i)
          bs[i] = ((c >> (bitoff + i)) & 1) ? (short)0x3C00 : (short)0;
        bmf[fn] = *(const f16x8*)&bs;
      }
#pragma unroll
      for (int fm = 0; fm < 4; ++fm)
#pragma unroll
        for (int fn = 0; fn < 4; ++fn)
          acc[fm][fn] = MFMAH(ah[fm], bmf[fn], acc[fm][fn]);
    }
    __syncthreads();
  }
#pragma unroll
  for (int fm = 0; fm < 4; ++fm)
#pragma unroll
    for (int fn = 0; fn < 4; ++fn) {
      int h = h0 + wh*64 + fm*16 + lk*4;
      int g = g0 + wg*64 + fn*16 + l15;
      u16x4 v4;
#pragma unroll
      for (int j = 0; j < 4; ++j) v4[j] = f16b(acc[fm][fn][j] * (1.0f/Nn));
      *(u16x4*)(p16 + ((size_t)(b*GP + g)) * Hh + h) = v4;
    }
}

// ---------------- finalq GEMM: fq[g][o] = Wcat@[pooled|lastE]^T + qg ----------
// grid(ot=2, gt=4, b=64), block(256)=2x2 waves, wave tile 64o x 64g, K=512, BK=64
__global__ __launch_bounds__(256, 2) void k_finalq(const int* __restrict__ last_node,
                                                   float* __restrict__ ws) {
  __shared__ __align__(16) unsigned short sA[128*64], sB[128*64];
  __shared__ int lL[128];
  int ot = blockIdx.x, gt = blockIdx.y, b = blockIdx.z;
  int t = threadIdx.x, w = t >> 6, lane = t & 63;
  int wo = w >> 1, wg = w & 1, l15 = lane & 15, lk = lane >> 4;
  const unsigned short* wc = (const unsigned short*)(ws + WS_WC16);
  const unsigned short* p16 = (const unsigned short*)(ws + WS_P16);
  const unsigned short* e16 = (const unsigned short*)(ws + WS_E16);
  unsigned short* f16 = (unsigned short*)(ws + WS_F16);
  int o0 = ot*128, g0 = gt*128;
  if (t < 128) lL[t] = last_node[b*Gg + ((g0 + t) < Gg ? (g0 + t) : Gg-1)];
  __syncthreads();
  f32x4 acc[4][4] = {};
  int srow = t >> 1, sc0 = (t & 1) * 4;
  size_t abase = ((size_t)(o0 + srow)) * 512;
  size_t pbase = ((size_t)(b*GP + g0 + srow)) * Hh;
  size_t lbase = ((size_t)(b*Nn + lL[srow])) * Hh;
  for (int st = 0; st < 8; ++st) {
    int k0 = st * 64;
#pragma unroll
    for (int i = 0; i < 4; ++i) {
      int cc = sc0 + i;
      int d = SW(srow, cc);
      *(short8*)&sA[d] = *(const short8*)(wc + abase + k0 + cc*8);
      if (k0 < 256)
        *(short8*)&sB[d] = *(const short8*)(p16 + pbase + k0 + cc*8);
      else
        *(short8*)&sB[d] = *(const short8*)(e16 + lbase + (k0 - 256) + cc*8);
    }
    __syncthreads();
#pragma unroll
    for (int kk = 0; kk < 64; kk += 32) {
      f16x8 a[4], bb[4];
#pragma unroll
      for (int fm = 0; fm < 4; ++fm)
        a[fm] = *(const f16x8*)&sA[SW(wo*64 + fm*16 + l15, (kk>>3) + lk)];
#pragma unroll
      for (int fn = 0; fn < 4; ++fn)
        bb[fn] = *(const f16x8*)&sB[SW(wg*64 + fn*16 + l15, (kk>>3) + lk)];
#pragma unroll
      for (int fm = 0; fm < 4; ++fm)
#pragma unroll
        for (int fn = 0; fn < 4; ++fn)
          acc[fm][fn] = MFMAH(a[fm], bb[fn], acc[fm][fn]);
    }
    __syncthreads();
  }
#pragma unroll
  for (int fm = 0; fm < 4; ++fm) {
    int o = o0 + wo*64 + fm*16 + lk*4;
    float4 qv = *(const float4*)(ws + WS_QG + b*Hh + o);
    float q4[4] = {qv.x, qv.y, qv.z, qv.w};
#pragma unroll
    for (int fn = 0; fn < 4; ++fn) {
      int g = g0 + wg*64 + fn*16 + l15;
      u16x4 v4;
#pragma unroll
      for (int j = 0; j < 4; ++j) v4[j] = f16b(acc[fm][fn][j] + q4[j]);
      *(u16x4*)(f16 + ((size_t)(b*GP + g)) * Hh + o) = v4;
    }
  }
}

// ---------------- score GEMM + fp16 p + rowsum atomics ----------------
// grid(nt=8, gt=4, b=64), block(256)=2x2 waves, wave tile 64n x 64g, K=256, BK=64
__global__ __launch_bounds__(256, 4) void k_score(const float* __restrict__ dists,
                                                  const int* __restrict__ last_node,
                                                  float* __restrict__ ws) {
  __shared__ __align__(16) unsigned short sE[128*64], sF[128*64];
  __shared__ int lL[128];
  int nt = blockIdx.x, gt = blockIdx.y, b = blockIdx.z;
  int t = threadIdx.x, w = t >> 6, lane = t & 63;
  int wn = w >> 1, wg = w & 1, l15 = lane & 15, lk = lane >> 4;
  const unsigned short* e16 = (const unsigned short*)(ws + WS_E16);
  const unsigned short* f16 = (const unsigned short*)(ws + WS_F16);
  const unsigned short* bmp = (const unsigned short*)(ws + WS_BM);
  unsigned short* po = (unsigned short*)(ws + WS_PO);
  float* rs = ws + WS_RS;
  int n0 = nt*128, g0 = gt*128;
  if (t < 128) lL[t] = last_node[b*Gg + ((g0 + t) < Gg ? (g0 + t) : Gg-1)];
  __syncthreads();
  f32x4 acc[4][4] = {};
  int srow = t >> 1, sc0 = (t & 1) * 4;
  int nr = n0 + srow; if (nr > Nn-1) nr = Nn-1;
  size_t ebase = ((size_t)(b*Nn + nr)) * Hh;
  size_t fbase = ((size_t)(b*GP + g0 + srow)) * Hh;
  for (int st = 0; st < 4; ++st) {
    int k0 = st * 64;
#pragma unroll
    for (int i = 0; i < 4; ++i) {
      int cc = sc0 + i;
      int d = SW(srow, cc);
      *(short8*)&sE[d] = *(const short8*)(e16 + ebase + k0 + cc*8);
      *(short8*)&sF[d] = *(const short8*)(f16 + fbase + k0 + cc*8);
    }
    __syncthreads();
#pragma unroll
    for (int kk = 0; kk < 64; kk += 32) {
      f16x8 a[4], bb[4];
#pragma unroll
      for (int fm = 0; fm < 4; ++fm)
        a[fm] = *(const f16x8*)&sE[SW(wn*64 + fm*16 + l15, (kk>>3) + lk)];
#pragma unroll
      for (int fn = 0; fn < 4; ++fn)
        bb[fn] = *(const f16x8*)&sF[SW(wg*64 + fn*16 + l15, (kk>>3) + lk)];
#pragma unroll
      for (int fm = 0; fm < 4; ++fm)
#pragma unroll
        for (int fn = 0; fn < 4; ++fn)
          acc[fm][fn] = MFMAH(a[fm], bb[fn], acc[fm][fn]);
    }
    __syncthreads();
  }
  const float c2 = 0.70710678118654752f;
  float rsum[4] = {0.f, 0.f, 0.f, 0.f};
#pragma unroll
  for (int fn = 0; fn < 4; ++fn) {
    int gl = wg*64 + fn*16 + l15;
    int g = g0 + gl;
    if (g < Gg) {
      int L = lL[gl];
      const float* drow = dists + ((size_t)(b*Nn + L)) * Nn;
      const unsigned short* bmr = bmp + ((size_t)(b*GP + g)) * 64;
      unsigned short* prow = po + ((size_t)(b*Gg + g)) * 1024;
#pragma unroll
      for (int fm = 0; fm < 4; ++fm) {
        int n = n0 + wn*64 + fm*16 + lk*4;
        if (n < Nn) {
          float4 d4 = *(const float4*)(drow + n);
          unsigned cb = bmr[n >> 4];
          int bo = n & 15;
          float dd[4] = {d4.x, d4.y, d4.z, d4.w};
          unsigned short h4[4];
#pragma unroll
          for (int j = 0; j < 4; ++j) {
            // p = exp(10*tanh(s) - 10), exp2-domain, rcp-approx division
            float s = fmaf(acc[fm][fn][j], 0.0625f, -dd[j] * c2);
            float e = __expf(-2.0f * fabsf(s));
            float r = __builtin_amdgcn_rcpf(1.0f + e);
            float m = fmaf(-20.0f, e * r, 10.0f);   // = 10*tanh(|s|)
            float parg = copysignf(m, s) - 10.0f;
            float p = ((cb >> (bo + j)) & 1) ? 0.f : __expf(parg);
            rsum[fn] += p;
            h4[j] = f16b(p);
          }
          uint2 u = { (unsigned)h4[0] | ((unsigned)h4[1] << 16),
                      (unsigned)h4[2] | ((unsigned)h4[3] << 16) };
          *(uint2*)(prow + n) = u;
        }
      }
    }
  }
#pragma unroll
  for (int fn = 0; fn < 4; ++fn) {
    rsum[fn] += __shfl_xor(rsum[fn], 16);
    rsum[fn] += __shfl_xor(rsum[fn], 32);
    int g = g0 + wg*64 + fn*16 + l15;
    if (lk == 0 && g < Gg) atomicAdd(rs + b*GP + g, rsum[fn]);
  }
}

// ---------------- normalize: out[g][n] = fp16 p * (1/rs): grid(31250) ---------
__global__ __launch_bounds__(256) void k_norm(const float* __restrict__ ws,
                                              float* __restrict__ out) {
  int idx = blockIdx.x * 256 + threadIdx.x;   // float4 index, < 8,000,000
  int bg = idx / 250;                         // b*Gg + g
  int n = (idx - bg * 250) * 4;
  int b = bg / Gg, g = bg - b * Gg;
  const unsigned short* po = (const unsigned short*)(ws + WS_PO);
  float inv = 1.0f / ws[WS_RS + b*GP + g];
  uint2 u = *(const uint2*)(po + (size_t)bg * 1024 + n);
  float4 o4;
  o4.x = __half2float(__ushort_as_half((unsigned short)(u.x & 0xFFFF))) * inv;
  o4.y = __half2float(__ushort_as_half((unsigned short)(u.x >> 16))) * inv;
  o4.z = __half2float(__ushort_as_half((unsigned short)(u.y & 0xFFFF))) * inv;
  o4.w = __half2float(__ushort_as_half((unsigned short)(u.y >> 16))) * inv;
  *(float4*)(out + (size_t)bg * Nn + n) = o4;
}

extern "C" void kernel_launch(void* const* d_in, const int* in_sizes, int n_in,
                              void* d_out, int out_size, void* d_ws, size_t ws_size,
                              hipStream_t stream) {
  const float* emb       = (const float*)d_in[0];
  const float* dists     = (const float*)d_in[1];
  const int*   last_node = (const int*)d_in[2];
  const float* gm        = (const float*)d_in[3];
  const float* Wg        = (const float*)d_in[4];
  const float* Wf        = (const float*)d_in[5];
  const float* Wl        = (const float*)d_in[6];
  const float* Wv        = (const float*)d_in[7];
  float* out = (float*)d_out;
  float* ws  = (float*)d_ws;

  hipLaunchKernelGGL(k_zero,   dim3(192),       dim3(256), 0, stream, ws);
  hipLaunchKernelGGL(k_prep,   dim3(16,4,Bb),   dim3(256), 0, stream, emb, ws);
  hipLaunchKernelGGL(k_qgraph, dim3(Bb),        dim3(256), 0, stream, Wg, ws);
  hipLaunchKernelGGL(k_wcat,   dim3(256),       dim3(256), 0, stream, Wf, Wl, Wv, ws);
  hipLaunchKernelGGL(k_bm,     dim3(Bb*GP/4),   dim3(256), 0, stream, gm, ws);
  hipLaunchKernelGGL(k_pool,   dim3(2,4,Bb),    dim3(256), 0, stream, ws);
  hipLaunchKernelGGL(k_finalq, dim3(2,4,Bb),    dim3(256), 0, stream, last_node, ws);
  hipLaunchKernelGGL(k_score,  dim3(8,4,Bb),    dim3(256), 0, stream, dists, last_node, ws);
  hipLaunchKernelGGL(k_norm,   dim3(31250),     dim3(256), 0, stream, ws, out);
}

// Round 11
// 321.330 us; speedup vs baseline: 1.2185x; 1.0172x over previous
//
#include <hip/hip_runtime.h>
#include <hip/hip_fp16.h>
#include <math.h>

#define Bb 64
#define Nn 1000
#define Gg 500
#define Hh 256
#define GP 512
#define NP 1024

// float offsets into d_ws (total 38.3M floats = 153 MB)
#define WS_MP   0u           // [B][H] fp32 column sums (zeroed each launch)
#define WS_QG   16384u       // [B][H] fp32 q_graph
#define WS_RS   32768u       // [B][GP] fp32 row sums (zeroed)
#define WS_BM   65536u       // u16 [B][GP][64] visited bitmask
#define WS_WC16 1114112u     // u16 [256][512] Wcat fp16
#define WS_E16  1179648u     // u16 [B][N][H] emb fp16 row-major
#define WS_T16  9371648u     // u16 [B][H][NP] embT fp16 (dead after k_pool)
#define WS_P16  17760256u    // u16 [B][GP][H] pooled fp16 (dead after k_finalq)
#define WS_F16  WS_T16       // u16 [B][GP][H] fq fp16 (overlays T16)
#define WS_PO   21954560u    // u16 [B][500][1024] unnorm p fp16

typedef __attribute__((ext_vector_type(8))) short short8;
typedef __attribute__((ext_vector_type(8))) _Float16 f16x8;
typedef __attribute__((ext_vector_type(4))) float f32x4;
typedef __attribute__((ext_vector_type(4))) unsigned short u16x4;

#define MFMAH(a,b,c) __builtin_amdgcn_mfma_f32_16x16x32_f16(a,b,c,0,0,0)
// swizzled LDS offset (shorts): 64-short rows, 8 chunks of 8 halves (16B)
#define SW(row, chunk) (((row) << 6) + ((((chunk) ^ ((row) & 7))) << 3))

__device__ __forceinline__ unsigned short f16b(float v) {
  return __half_as_ushort(__float2half(v));
}

// ---------------- zero MP + RS: grid(192), block(256) ----------------
__global__ __launch_bounds__(256) void k_zero(float* __restrict__ ws) {
  int bid = blockIdx.x, t = threadIdx.x;
  if (bid < 64) ws[WS_MP + bid * 256 + t] = 0.f;
  else          ws[WS_RS + (bid - 64) * 256 + t] = 0.f;
}

// ---------------- prep: emb -> e16 + t16 + column sums (vectorized) ----------
// grid(nt=16, ht=4, b=64), block(256)
__global__ __launch_bounds__(256) void k_prep(const float* __restrict__ emb,
                                              float* __restrict__ ws) {
  __shared__ float tile[64][68];     // stride 68 floats = 272 B = 17*16 -> f4-aligned
  __shared__ float colsum[16][64];
  int nt = blockIdx.x, ht = blockIdx.y, b = blockIdx.z;
  int t = threadIdx.x;
  int c4 = (t & 15) * 4, r0 = t >> 4;
  int n0 = nt * 64, h0 = ht * 64;
  unsigned short* e16 = (unsigned short*)(ws + WS_E16);
  unsigned short* t16 = (unsigned short*)(ws + WS_T16);
  float cs0 = 0.f, cs1 = 0.f, cs2 = 0.f, cs3 = 0.f;
#pragma unroll
  for (int rr = 0; rr < 4; ++rr) {
    int r = r0 + rr * 16;
    int n = n0 + r;
    float4 v = {0.f, 0.f, 0.f, 0.f};
    if (n < Nn) {
      size_t idx = ((size_t)(b * Nn + n)) * Hh + h0 + c4;
      v = *(const float4*)(emb + idx);
      u16x4 e4 = { f16b(v.x), f16b(v.y), f16b(v.z), f16b(v.w) };
      *(u16x4*)(e16 + idx) = e4;
    }
    *(float4*)&tile[r][c4] = v;
    cs0 += v.x; cs1 += v.y; cs2 += v.z; cs3 += v.w;
  }
  colsum[r0][c4 + 0] = cs0; colsum[r0][c4 + 1] = cs1;
  colsum[r0][c4 + 2] = cs2; colsum[r0][c4 + 3] = cs3;
  __syncthreads();
  {
    int h_l = t >> 2, nseg = t & 3;
    short8 h8a, h8b;
#pragma unroll
    for (int i = 0; i < 16; ++i) {
      float v = tile[nseg * 16 + i][h_l];
      unsigned short hv = f16b(v);
      if (i < 8) h8a[i] = (short)hv;
      else       h8b[i-8] = (short)hv;
    }
    size_t base = ((size_t)(b * Hh + h0 + h_l)) * NP + n0 + nseg * 16;
    *(short8*)(t16 + base) = h8a; *(short8*)(t16 + base + 8) = h8b;
  }
  if (t < 64) {
    float s = 0.f;
#pragma unroll
    for (int i = 0; i < 16; ++i) s += colsum[i][t];
    atomicAdd(ws + WS_MP + b * Hh + h0 + t, s);
  }
}

// ---------------- q_graph: grid(B), block(256) ----------------
__global__ __launch_bounds__(256) void k_qgraph(const float* __restrict__ Wg,
                                                float* __restrict__ ws) {
  __shared__ float mean[Hh];
  int b = blockIdx.x, t = threadIdx.x;
  mean[t] = ws[WS_MP + b*Hh + t] * (1.0f/Nn);
  __syncthreads();
  const float4* wrow = (const float4*)(Wg + (size_t)t * Hh);
  float acc = 0.f;
#pragma unroll
  for (int h4 = 0; h4 < Hh/4; ++h4) {
    float4 w = wrow[h4];
    acc += mean[h4*4]*w.x + mean[h4*4+1]*w.y + mean[h4*4+2]*w.z + mean[h4*4+3]*w.w;
  }
  ws[WS_QG + b*Hh + t] = acc;
}

// ---------------- Wcat fp16: grid(256), block(256) ----------------
__global__ __launch_bounds__(256) void k_wcat(const float* __restrict__ Wf,
                                              const float* __restrict__ Wl,
                                              const float* __restrict__ Wv,
                                              float* __restrict__ ws) {
  int o = blockIdx.x, k = threadIdx.x;
  unsigned short* wc = (unsigned short*)(ws + WS_WC16);
  wc[o*512 + k]       = f16b(Wv[o*Hh + k]);
  wc[o*512 + 256 + k] = f16b(Wl[o*Hh + k] + Wf[o*Hh + k]);
}

// ---------------- bitmask: gm -> 1 bit per (b,g,n): grid(B*GP/4), block(256) ----
__global__ __launch_bounds__(256) void k_bm(const float* __restrict__ gm,
                                            float* __restrict__ ws) {
  int w = threadIdx.x >> 6, l = threadIdx.x & 63;
  int row = blockIdx.x * 4 + w;          // b*GP + g
  int b = row >> 9, g = row & 511;
  unsigned long long* dst = (unsigned long long*)((unsigned short*)(ws + WS_BM) + (size_t)row * 64);
  if (g < Gg) {
    const float* src = gm + ((size_t)b * Gg + g) * Nn;
#pragma unroll
    for (int i = 0; i < 16; ++i) {
      int n = i * 64 + l;
      bool bit = (n < Nn) ? (src[n] < -1e30f) : false;
      unsigned long long m = __ballot(bit);
      if (l == i) dst[i] = m;
    }
  } else {
    if (l < 16) dst[l] = 0ull;
  }
}

// ---------------- pool GEMM: pooled[g][h] = (1/N) mask @ emb ----------------
// grid(ht=2, gt=4, b=64), block(256)=2x2 waves, wave tile 64h x 64g, BK=64
__global__ __launch_bounds__(256, 2) void k_pool(float* __restrict__ ws) {
  __shared__ __align__(16) unsigned short sT[128*64];
  int ht = blockIdx.x, gt = blockIdx.y, b = blockIdx.z;
  int t = threadIdx.x, w = t >> 6, lane = t & 63;
  int wh = w >> 1, wg = w & 1, l15 = lane & 15, lk = lane >> 4;
  const unsigned short* t16 = (const unsigned short*)(ws + WS_T16);
  const unsigned short* bmp = (const unsigned short*)(ws + WS_BM);
  unsigned short* p16 = (unsigned short*)(ws + WS_P16);
  int h0 = ht*128, g0 = gt*128;
  f32x4 acc[4][4] = {};
  const unsigned short* brow[4];
#pragma unroll
  for (int fn = 0; fn < 4; ++fn) {
    int g = g0 + wg*64 + fn*16 + l15; if (g > Gg-1) g = Gg-1;
    brow[fn] = bmp + ((size_t)(b*GP + g)) * 64;
  }
  int bitoff = (lk & 1) * 8;
  int srow = t >> 1, sc0 = (t & 1) * 4;
  size_t sbase = ((size_t)(b*Hh + h0 + srow)) * NP;
  for (int st = 0; st < 16; ++st) {
    int k0 = st * 64;
#pragma unroll
    for (int i = 0; i < 4; ++i) {
      int cc = sc0 + i;
      *(short8*)&sT[SW(srow, cc)] = *(const short8*)(t16 + sbase + k0 + cc*8);
    }
    __syncthreads();
#pragma unroll
    for (int kk = 0; kk < 64; kk += 32) {
      f16x8 ah[4], bmf[4];
#pragma unroll
      for (int fm = 0; fm < 4; ++fm)
        ah[fm] = *(const f16x8*)&sT[SW(wh*64 + fm*16 + l15, (kk>>3) + lk)];
#pragma unroll
      for (int fn = 0; fn < 4; ++fn) {
        unsigned c = brow[fn][((k0 + kk) >> 4) + (lk >> 1)];
        short8 bs;
#pragma unroll
        for (int i = 0; i < 8; ++i)
          bs[i] = ((c >> (bitoff + i)) & 1) ? (short)0x3C00 : (short)0;
        bmf[fn] = *(const f16x8*)&bs;
      }
#pragma unroll
      for (int fm = 0; fm < 4; ++fm)
#pragma unroll
        for (int fn = 0; fn < 4; ++fn)
          acc[fm][fn] = MFMAH(ah[fm], bmf[fn], acc[fm][fn]);
    }
    __syncthreads();
  }
#pragma unroll
  for (int fm = 0; fm < 4; ++fm)
#pragma unroll
    for (int fn = 0; fn < 4; ++fn) {
      int h = h0 + wh*64 + fm*16 + lk*4;
      int g = g0 + wg*64 + fn*16 + l15;
      u16x4 v4;
#pragma unroll
      for (int j = 0; j < 4; ++j) v4[j] = f16b(acc[fm][fn][j] * (1.0f/Nn));
      *(u16x4*)(p16 + ((size_t)(b*GP + g)) * Hh + h) = v4;
    }
}

// ---------------- finalq GEMM: fq[g][o] = Wcat@[pooled|lastE]^T + qg ----------
// grid(ot=2, gt=4, b=64), block(256)=2x2 waves, wave tile 64o x 64g, K=512, BK=64
__global__ __launch_bounds__(256, 2) void k_finalq(const int* __restrict__ last_node,
                                                   float* __restrict__ ws) {
  __shared__ __align__(16) unsigned short sA[128*64], sB[128*64];
  __shared__ int lL[128];
  int ot = blockIdx.x, gt = blockIdx.y, b = blockIdx.z;
  int t = threadIdx.x, w = t >> 6, lane = t & 63;
  int wo = w >> 1, wg = w & 1, l15 = lane & 15, lk = lane >> 4;
  const unsigned short* wc = (const unsigned short*)(ws + WS_WC16);
  const unsigned short* p16 = (const unsigned short*)(ws + WS_P16);
  const unsigned short* e16 = (const unsigned short*)(ws + WS_E16);
  unsigned short* f16 = (unsigned short*)(ws + WS_F16);
  int o0 = ot*128, g0 = gt*128;
  if (t < 128) lL[t] = last_node[b*Gg + ((g0 + t) < Gg ? (g0 + t) : Gg-1)];
  __syncthreads();
  f32x4 acc[4][4] = {};
  int srow = t >> 1, sc0 = (t & 1) * 4;
  size_t abase = ((size_t)(o0 + srow)) * 512;
  size_t pbase = ((size_t)(b*GP + g0 + srow)) * Hh;
  size_t lbase = ((size_t)(b*Nn + lL[srow])) * Hh;
  for (int st = 0; st < 8; ++st) {
    int k0 = st * 64;
#pragma unroll
    for (int i = 0; i < 4; ++i) {
      int cc = sc0 + i;
      int d = SW(srow, cc);
      *(short8*)&sA[d] = *(const short8*)(wc + abase + k0 + cc*8);
      if (k0 < 256)
        *(short8*)&sB[d] = *(const short8*)(p16 + pbase + k0 + cc*8);
      else
        *(short8*)&sB[d] = *(const short8*)(e16 + lbase + (k0 - 256) + cc*8);
    }
    __syncthreads();
#pragma unroll
    for (int kk = 0; kk < 64; kk += 32) {
      f16x8 a[4], bb[4];
#pragma unroll
      for (int fm = 0; fm < 4; ++fm)
        a[fm] = *(const f16x8*)&sA[SW(wo*64 + fm*16 + l15, (kk>>3) + lk)];
#pragma unroll
      for (int fn = 0; fn < 4; ++fn)
        bb[fn] = *(const f16x8*)&sB[SW(wg*64 + fn*16 + l15, (kk>>3) + lk)];
#pragma unroll
      for (int fm = 0; fm < 4; ++fm)
#pragma unroll
        for (int fn = 0; fn < 4; ++fn)
          acc[fm][fn] = MFMAH(a[fm], bb[fn], acc[fm][fn]);
    }
    __syncthreads();
  }
#pragma unroll
  for (int fm = 0; fm < 4; ++fm) {
    int o = o0 + wo*64 + fm*16 + lk*4;
    float4 qv = *(const float4*)(ws + WS_QG + b*Hh + o);
    float q4[4] = {qv.x, qv.y, qv.z, qv.w};
#pragma unroll
    for (int fn = 0; fn < 4; ++fn) {
      int g = g0 + wg*64 + fn*16 + l15;
      u16x4 v4;
#pragma unroll
      for (int j = 0; j < 4; ++j) v4[j] = f16b(acc[fm][fn][j] + q4[j]);
      *(u16x4*)(f16 + ((size_t)(b*GP + g)) * Hh + o) = v4;
    }
  }
}

// ---------------- score GEMM + fp16 p + rowsum atomics ----------------
// grid(gt=4, nt=8, b=64), block(256)=2x2 waves, wave tile 64n x 64g, K=256, BK=64
// x=gt so the 4 consecutively-dispatched blocks share the same e-tile (L2).
__global__ __launch_bounds__(256, 4) void k_score(const float* __restrict__ dists,
                                                  const int* __restrict__ last_node,
                                                  float* __restrict__ ws) {
  __shared__ __align__(16) unsigned short sE[128*64], sF[128*64];
  __shared__ int lL[128];
  int gt = blockIdx.x, nt = blockIdx.y, b = blockIdx.z;
  int t = threadIdx.x, w = t >> 6, lane = t & 63;
  int wn = w >> 1, wg = w & 1, l15 = lane & 15, lk = lane >> 4;
  const unsigned short* e16 = (const unsigned short*)(ws + WS_E16);
  const unsigned short* f16 = (const unsigned short*)(ws + WS_F16);
  const unsigned short* bmp = (const unsigned short*)(ws + WS_BM);
  unsigned short* po = (unsigned short*)(ws + WS_PO);
  float* rs = ws + WS_RS;
  int n0 = nt*128, g0 = gt*128;
  if (t < 128) lL[t] = last_node[b*Gg + ((g0 + t) < Gg ? (g0 + t) : Gg-1)];
  __syncthreads();
  f32x4 acc[4][4] = {};
  int srow = t >> 1, sc0 = (t & 1) * 4;
  int nr = n0 + srow; if (nr > Nn-1) nr = Nn-1;
  size_t ebase = ((size_t)(b*Nn + nr)) * Hh;
  size_t fbase = ((size_t)(b*GP + g0 + srow)) * Hh;
  for (int st = 0; st < 4; ++st) {
    int k0 = st * 64;
#pragma unroll
    for (int i = 0; i < 4; ++i) {
      int cc = sc0 + i;
      int d = SW(srow, cc);
      *(short8*)&sE[d] = *(const short8*)(e16 + ebase + k0 + cc*8);
      *(short8*)&sF[d] = *(const short8*)(f16 + fbase + k0 + cc*8);
    }
    __syncthreads();
#pragma unroll
    for (int kk = 0; kk < 64; kk += 32) {
      f16x8 a[4], bb[4];
#pragma unroll
      for (int fm = 0; fm < 4; ++fm)
        a[fm] = *(const f16x8*)&sE[SW(wn*64 + fm*16 + l15, (kk>>3) + lk)];
#pragma unroll
      for (int fn = 0; fn < 4; ++fn)
        bb[fn] = *(const f16x8*)&sF[SW(wg*64 + fn*16 + l15, (kk>>3) + lk)];
#pragma unroll
      for (int fm = 0; fm < 4; ++fm)
#pragma unroll
        for (int fn = 0; fn < 4; ++fn)
          acc[fm][fn] = MFMAH(a[fm], bb[fn], acc[fm][fn]);
    }
    __syncthreads();
  }
  const float c2 = 0.70710678118654752f;
  float rsum[4] = {0.f, 0.f, 0.f, 0.f};
#pragma unroll
  for (int fn = 0; fn < 4; ++fn) {
    int gl = wg*64 + fn*16 + l15;
    int g = g0 + gl;
    if (g < Gg) {
      int L = lL[gl];
      const float* drow = dists + ((size_t)(b*Nn + L)) * Nn;
      const unsigned short* bmr = bmp + ((size_t)(b*GP + g)) * 64;
      unsigned short* prow = po + ((size_t)(b*Gg + g)) * 1024;
#pragma unroll
      for (int fm = 0; fm < 4; ++fm) {
        int n = n0 + wn*64 + fm*16 + lk*4;
        if (n < Nn) {
          float4 d4 = *(const float4*)(drow + n);
          unsigned cb = bmr[n >> 4];
          int bo = n & 15;
          float dd[4] = {d4.x, d4.y, d4.z, d4.w};
          unsigned short h4[4];
#pragma unroll
          for (int j = 0; j < 4; ++j) {
            // p = exp(10*tanh(s) - 10), exp2-domain, rcp-approx division
            float s = fmaf(acc[fm][fn][j], 0.0625f, -dd[j] * c2);
            float e = __expf(-2.0f * fabsf(s));
            float r = __builtin_amdgcn_rcpf(1.0f + e);
            float m = fmaf(-20.0f, e * r, 10.0f);   // = 10*tanh(|s|)
            float parg = copysignf(m, s) - 10.0f;
            float p = ((cb >> (bo + j)) & 1) ? 0.f : __expf(parg);
            rsum[fn] += p;
            h4[j] = f16b(p);
          }
          uint2 u = { (unsigned)h4[0] | ((unsigned)h4[1] << 16),
                      (unsigned)h4[2] | ((unsigned)h4[3] << 16) };
          *(uint2*)(prow + n) = u;
        }
      }
    }
  }
#pragma unroll
  for (int fn = 0; fn < 4; ++fn) {
    rsum[fn] += __shfl_xor(rsum[fn], 16);
    rsum[fn] += __shfl_xor(rsum[fn], 32);
    int g = g0 + wg*64 + fn*16 + l15;
    if (lk == 0 && g < Gg) atomicAdd(rs + b*GP + g, rsum[fn]);
  }
}

// ---------------- normalize (wide): out[g][n] = fp16 p * (1/rs): grid(15625) --
__global__ __launch_bounds__(256) void k_norm(const float* __restrict__ ws,
                                              float* __restrict__ out) {
  int idx = blockIdx.x * 256 + threadIdx.x;   // 8-elem index, total 4,000,000
  int bg = idx / 125;                         // b*Gg + g
  int n = (idx - bg * 125) * 8;
  int b = bg / Gg, g = bg - b * Gg;
  const unsigned short* po = (const unsigned short*)(ws + WS_PO);
  float inv = 1.0f / ws[WS_RS + b*GP + g];
  uint4 u = *(const uint4*)(po + (size_t)bg * 1024 + n);
  float* orow = out + (size_t)bg * Nn + n;
  float4 o0, o1;
  o0.x = __half2float(__ushort_as_half((unsigned short)(u.x & 0xFFFF))) * inv;
  o0.y = __half2float(__ushort_as_half((unsigned short)(u.x >> 16))) * inv;
  o0.z = __half2float(__ushort_as_half((unsigned short)(u.y & 0xFFFF))) * inv;
  o0.w = __half2float(__ushort_as_half((unsigned short)(u.y >> 16))) * inv;
  o1.x = __half2float(__ushort_as_half((unsigned short)(u.z & 0xFFFF))) * inv;
  o1.y = __half2float(__ushort_as_half((unsigned short)(u.z >> 16))) * inv;
  o1.z = __half2float(__ushort_as_half((unsigned short)(u.w & 0xFFFF))) * inv;
  o1.w = __half2float(__ushort_as_half((unsigned short)(u.w >> 16))) * inv;
  *(float4*)orow = o0;
  *(float4*)(orow + 4) = o1;
}

extern "C" void kernel_launch(void* const* d_in, const int* in_sizes, int n_in,
                              void* d_out, int out_size, void* d_ws, size_t ws_size,
                              hipStream_t stream) {
  const float* emb       = (const float*)d_in[0];
  const float* dists     = (const float*)d_in[1];
  const int*   last_node = (const int*)d_in[2];
  const float* gm        = (const float*)d_in[3];
  const float* Wg        = (const float*)d_in[4];
  const float* Wf        = (const float*)d_in[5];
  const float* Wl        = (const float*)d_in[6];
  const float* Wv        = (const float*)d_in[7];
  float* out = (float*)d_out;
  float* ws  = (float*)d_ws;

  hipLaunchKernelGGL(k_zero,   dim3(192),       dim3(256), 0, stream, ws);
  hipLaunchKernelGGL(k_prep,   dim3(16,4,Bb),   dim3(256), 0, stream, emb, ws);
  hipLaunchKernelGGL(k_qgraph, dim3(Bb),        dim3(256), 0, stream, Wg, ws);
  hipLaunchKernelGGL(k_wcat,   dim3(256),       dim3(256), 0, stream, Wf, Wl, Wv, ws);
  hipLaunchKernelGGL(k_bm,     dim3(Bb*GP/4),   dim3(256), 0, stream, gm, ws);
  hipLaunchKernelGGL(k_pool,   dim3(2,4,Bb),    dim3(256), 0, stream, ws);
  hipLaunchKernelGGL(k_finalq, dim3(2,4,Bb),    dim3(256), 0, stream, last_node, ws);
  hipLaunchKernelGGL(k_score,  dim3(4,8,Bb),    dim3(256), 0, stream, dists, last_node, ws);
  hipLaunchKernelGGL(k_norm,   dim3(15625),     dim3(256), 0, stream, ws, out);
}

// Round 12
// 304.076 us; speedup vs baseline: 1.2876x; 1.0567x over previous
//
#include <hip/hip_runtime.h>
#include <hip/hip_fp16.h>
#include <math.h>

#define Bb 64
#define Nn 1000
#define Gg 500
#define Hh 256
#define GP 512
#define NP 1024

// float offsets into d_ws (total 38,584,320 floats = 154 MB)
#define WS_QG   0u           // [B][H] fp32 q_graph
#define WS_RS   16384u       // [B][GP] fp32 row sums (zeroed by k_misc)
#define WS_BM   49152u       // u16 [B][GP][64] visited bitmask
#define WS_WC16 1097728u     // u16 [256][512] Wcat fp16
#define WS_E16  1163264u     // u16 [B][N][H] emb fp16 row-major
#define WS_T16  9355264u     // u16 [B][H][NP] embT fp16 (dead after k_pool)
#define WS_P16  17743872u    // u16 [B][GP][H] pooled fp16 (dead after k_finalq)
#define WS_F16  WS_T16       // u16 [B][GP][H] fq fp16 (overlays T16)
#define WS_PO   21938176u    // u16 [B][500][1024] unnorm p fp16
#define WS_MP   38322176u    // [B][H][16] fp32 column-sum partials (no zero needed)

typedef __attribute__((ext_vector_type(8))) short short8;
typedef __attribute__((ext_vector_type(8))) _Float16 f16x8;
typedef __attribute__((ext_vector_type(4))) float f32x4;
typedef __attribute__((ext_vector_type(4))) unsigned short u16x4;

#define MFMAH(a,b,c) __builtin_amdgcn_mfma_f32_16x16x32_f16(a,b,c,0,0,0)
// swizzled LDS offset (shorts): 64-short rows, 8 chunks of 8 halves (16B)
#define SW(row, chunk) (((row) << 6) + ((((chunk) ^ ((row) & 7))) << 3))

__device__ __forceinline__ unsigned short f16b(float v) {
  return __half_as_ushort(__float2half(v));
}

// ---------------- misc: bm (bid<8192) + wcat (8192..8447) + zero RS ----------
__global__ __launch_bounds__(256) void k_misc(const float* __restrict__ gm,
                                              const float* __restrict__ Wf,
                                              const float* __restrict__ Wl,
                                              const float* __restrict__ Wv,
                                              float* __restrict__ ws) {
  int bid = blockIdx.x, t = threadIdx.x;
  if (bid < 8192) {
    int w = t >> 6, l = t & 63;
    int row = bid * 4 + w;          // b*GP + g
    int b = row >> 9, g = row & 511;
    unsigned long long* dst = (unsigned long long*)((unsigned short*)(ws + WS_BM) + (size_t)row * 64);
    if (g < Gg) {
      const float* src = gm + ((size_t)b * Gg + g) * Nn;
#pragma unroll
      for (int i = 0; i < 16; ++i) {
        int n = i * 64 + l;
        bool bit = (n < Nn) ? (src[n] < -1e30f) : false;
        unsigned long long m = __ballot(bit);
        if (l == i) dst[i] = m;
      }
    } else {
      if (l < 16) dst[l] = 0ull;
    }
  } else if (bid < 8448) {
    int o = bid - 8192, k = t;
    unsigned short* wc = (unsigned short*)(ws + WS_WC16);
    wc[o*512 + k]       = f16b(Wv[o*Hh + k]);
    wc[o*512 + 256 + k] = f16b(Wl[o*Hh + k] + Wf[o*Hh + k]);
  } else {
    ws[WS_RS + (bid - 8448) * 256 + t] = 0.f;
  }
}

// ---------------- prep: emb -> e16 + t16 + column-sum partials ----------------
// grid(nt=16, ht=4, b=64), block(256)
__global__ __launch_bounds__(256) void k_prep(const float* __restrict__ emb,
                                              float* __restrict__ ws) {
  __shared__ float tile[64][68];     // stride 68 floats = 272 B -> f4-aligned
  __shared__ float colsum[16][64];
  int nt = blockIdx.x, ht = blockIdx.y, b = blockIdx.z;
  int t = threadIdx.x;
  int c4 = (t & 15) * 4, r0 = t >> 4;
  int n0 = nt * 64, h0 = ht * 64;
  unsigned short* e16 = (unsigned short*)(ws + WS_E16);
  unsigned short* t16 = (unsigned short*)(ws + WS_T16);
  float cs0 = 0.f, cs1 = 0.f, cs2 = 0.f, cs3 = 0.f;
#pragma unroll
  for (int rr = 0; rr < 4; ++rr) {
    int r = r0 + rr * 16;
    int n = n0 + r;
    float4 v = {0.f, 0.f, 0.f, 0.f};
    if (n < Nn) {
      size_t idx = ((size_t)(b * Nn + n)) * Hh + h0 + c4;
      v = *(const float4*)(emb + idx);
      u16x4 e4 = { f16b(v.x), f16b(v.y), f16b(v.z), f16b(v.w) };
      *(u16x4*)(e16 + idx) = e4;
    }
    *(float4*)&tile[r][c4] = v;
    cs0 += v.x; cs1 += v.y; cs2 += v.z; cs3 += v.w;
  }
  colsum[r0][c4 + 0] = cs0; colsum[r0][c4 + 1] = cs1;
  colsum[r0][c4 + 2] = cs2; colsum[r0][c4 + 3] = cs3;
  __syncthreads();
  {
    int h_l = t >> 2, nseg = t & 3;
    short8 h8a, h8b;
#pragma unroll
    for (int i = 0; i < 16; ++i) {
      float v = tile[nseg * 16 + i][h_l];
      unsigned short hv = f16b(v);
      if (i < 8) h8a[i] = (short)hv;
      else       h8b[i-8] = (short)hv;
    }
    size_t base = ((size_t)(b * Hh + h0 + h_l)) * NP + n0 + nseg * 16;
    *(short8*)(t16 + base) = h8a; *(short8*)(t16 + base + 8) = h8b;
  }
  if (t < 64) {
    float s = 0.f;
#pragma unroll
    for (int i = 0; i < 16; ++i) s += colsum[i][t];
    ws[WS_MP + (((size_t)(b * Hh + h0 + t)) << 4) + nt] = s;
  }
}

// ---------------- q_graph: grid(B), block(256) ----------------
__global__ __launch_bounds__(256) void k_qgraph(const float* __restrict__ Wg,
                                                float* __restrict__ ws) {
  __shared__ float mean[Hh];
  int b = blockIdx.x, t = threadIdx.x;
  {
    const float4* mp4 = (const float4*)(ws + WS_MP + (((size_t)(b * Hh + t)) << 4));
    float s = 0.f;
#pragma unroll
    for (int q = 0; q < 4; ++q) {
      float4 v = mp4[q];
      s += v.x + v.y + v.z + v.w;
    }
    mean[t] = s * (1.0f/Nn);
  }
  __syncthreads();
  const float4* wrow = (const float4*)(Wg + (size_t)t * Hh);
  float acc = 0.f;
#pragma unroll
  for (int h4 = 0; h4 < Hh/4; ++h4) {
    float4 w = wrow[h4];
    acc += mean[h4*4]*w.x + mean[h4*4+1]*w.y + mean[h4*4+2]*w.z + mean[h4*4+3]*w.w;
  }
  ws[WS_QG + b*Hh + t] = acc;
}

// ---------------- pool GEMM: pooled[g][h] = (1/N) mask @ emb ----------------
// grid(ht=2, gt=4, b=64), block(256)=2x2 waves, wave tile 64h x 64g, BK=64
__global__ __launch_bounds__(256, 2) void k_pool(float* __restrict__ ws) {
  __shared__ __align__(16) unsigned short sT[128*64];
  int ht = blockIdx.x, gt = blockIdx.y, b = blockIdx.z;
  int t = threadIdx.x, w = t >> 6, lane = t & 63;
  int wh = w >> 1, wg = w & 1, l15 = lane & 15, lk = lane >> 4;
  const unsigned short* t16 = (const unsigned short*)(ws + WS_T16);
  const unsigned short* bmp = (const unsigned short*)(ws + WS_BM);
  unsigned short* p16 = (unsigned short*)(ws + WS_P16);
  int h0 = ht*128, g0 = gt*128;
  f32x4 acc[4][4] = {};
  const unsigned short* brow[4];
#pragma unroll
  for (int fn = 0; fn < 4; ++fn) {
    int g = g0 + wg*64 + fn*16 + l15; if (g > Gg-1) g = Gg-1;
    brow[fn] = bmp + ((size_t)(b*GP + g)) * 64;
  }
  int bitoff = (lk & 1) * 8;
  int srow = t >> 1, sc0 = (t & 1) * 4;
  size_t sbase = ((size_t)(b*Hh + h0 + srow)) * NP;
  for (int st = 0; st < 16; ++st) {
    int k0 = st * 64;
#pragma unroll
    for (int i = 0; i < 4; ++i) {
      int cc = sc0 + i;
      *(short8*)&sT[SW(srow, cc)] = *(const short8*)(t16 + sbase + k0 + cc*8);
    }
    __syncthreads();
#pragma unroll
    for (int kk = 0; kk < 64; kk += 32) {
      f16x8 ah[4], bmf[4];
#pragma unroll
      for (int fm = 0; fm < 4; ++fm)
        ah[fm] = *(const f16x8*)&sT[SW(wh*64 + fm*16 + l15, (kk>>3) + lk)];
#pragma unroll
      for (int fn = 0; fn < 4; ++fn) {
        unsigned c = brow[fn][((k0 + kk) >> 4) + (lk >> 1)];
        short8 bs;
#pragma unroll
        for (int i = 0; i < 8; ++i)
          bs[i] = ((c >> (bitoff + i)) & 1) ? (short)0x3C00 : (short)0;
        bmf[fn] = *(const f16x8*)&bs;
      }
#pragma unroll
      for (int fm = 0; fm < 4; ++fm)
#pragma unroll
        for (int fn = 0; fn < 4; ++fn)
          acc[fm][fn] = MFMAH(ah[fm], bmf[fn], acc[fm][fn]);
    }
    __syncthreads();
  }
#pragma unroll
  for (int fm = 0; fm < 4; ++fm)
#pragma unroll
    for (int fn = 0; fn < 4; ++fn) {
      int h = h0 + wh*64 + fm*16 + lk*4;
      int g = g0 + wg*64 + fn*16 + l15;
      u16x4 v4;
#pragma unroll
      for (int j = 0; j < 4; ++j) v4[j] = f16b(acc[fm][fn][j] * (1.0f/Nn));
      *(u16x4*)(p16 + ((size_t)(b*GP + g)) * Hh + h) = v4;
    }
}

// ---------------- finalq GEMM: fq[g][o] = Wcat@[pooled|lastE]^T + qg ----------
// grid(ot=2, gt=4, b=64), block(256)=2x2 waves, wave tile 64o x 64g, K=512, BK=64
__global__ __launch_bounds__(256, 2) void k_finalq(const int* __restrict__ last_node,
                                                   float* __restrict__ ws) {
  __shared__ __align__(16) unsigned short sA[128*64], sB[128*64];
  __shared__ int lL[128];
  int ot = blockIdx.x, gt = blockIdx.y, b = blockIdx.z;
  int t = threadIdx.x, w = t >> 6, lane = t & 63;
  int wo = w >> 1, wg = w & 1, l15 = lane & 15, lk = lane >> 4;
  const unsigned short* wc = (const unsigned short*)(ws + WS_WC16);
  const unsigned short* p16 = (const unsigned short*)(ws + WS_P16);
  const unsigned short* e16 = (const unsigned short*)(ws + WS_E16);
  unsigned short* f16 = (unsigned short*)(ws + WS_F16);
  int o0 = ot*128, g0 = gt*128;
  if (t < 128) lL[t] = last_node[b*Gg + ((g0 + t) < Gg ? (g0 + t) : Gg-1)];
  __syncthreads();
  f32x4 acc[4][4] = {};
  int srow = t >> 1, sc0 = (t & 1) * 4;
  size_t abase = ((size_t)(o0 + srow)) * 512;
  size_t pbase = ((size_t)(b*GP + g0 + srow)) * Hh;
  size_t lbase = ((size_t)(b*Nn + lL[srow])) * Hh;
  for (int st = 0; st < 8; ++st) {
    int k0 = st * 64;
#pragma unroll
    for (int i = 0; i < 4; ++i) {
      int cc = sc0 + i;
      int d = SW(srow, cc);
      *(short8*)&sA[d] = *(const short8*)(wc + abase + k0 + cc*8);
      if (k0 < 256)
        *(short8*)&sB[d] = *(const short8*)(p16 + pbase + k0 + cc*8);
      else
        *(short8*)&sB[d] = *(const short8*)(e16 + lbase + (k0 - 256) + cc*8);
    }
    __syncthreads();
#pragma unroll
    for (int kk = 0; kk < 64; kk += 32) {
      f16x8 a[4], bb[4];
#pragma unroll
      for (int fm = 0; fm < 4; ++fm)
        a[fm] = *(const f16x8*)&sA[SW(wo*64 + fm*16 + l15, (kk>>3) + lk)];
#pragma unroll
      for (int fn = 0; fn < 4; ++fn)
        bb[fn] = *(const f16x8*)&sB[SW(wg*64 + fn*16 + l15, (kk>>3) + lk)];
#pragma unroll
      for (int fm = 0; fm < 4; ++fm)
#pragma unroll
        for (int fn = 0; fn < 4; ++fn)
          acc[fm][fn] = MFMAH(a[fm], bb[fn], acc[fm][fn]);
    }
    __syncthreads();
  }
#pragma unroll
  for (int fm = 0; fm < 4; ++fm) {
    int o = o0 + wo*64 + fm*16 + lk*4;
    float4 qv = *(const float4*)(ws + WS_QG + b*Hh + o);
    float q4[4] = {qv.x, qv.y, qv.z, qv.w};
#pragma unroll
    for (int fn = 0; fn < 4; ++fn) {
      int g = g0 + wg*64 + fn*16 + l15;
      u16x4 v4;
#pragma unroll
      for (int j = 0; j < 4; ++j) v4[j] = f16b(acc[fm][fn][j] + q4[j]);
      *(u16x4*)(f16 + ((size_t)(b*GP + g)) * Hh + o) = v4;
    }
  }
}

// ---------------- score GEMM + fp16 p + rowsum atomics ----------------
// 1D grid 2048, XCD-swizzled decode -> (gt,nt,b); block(256)=2x2 waves,
// wave tile 64n x 64g, K=256, BK=64. Same-XCD neighbors share the e-tile.
__global__ __launch_bounds__(256, 4) void k_score(const float* __restrict__ dists,
                                                  const int* __restrict__ last_node,
                                                  float* __restrict__ ws) {
  __shared__ __align__(16) unsigned short sE[128*64], sF[128*64];
  __shared__ int lL[128];
  int id = blockIdx.x;
  int swz = ((id & 7) << 8) | (id >> 3);   // bijective: 2048 = 8 * 256
  int gt = swz & 3, nt = (swz >> 2) & 7, b = swz >> 5;
  int t = threadIdx.x, w = t >> 6, lane = t & 63;
  int wn = w >> 1, wg = w & 1, l15 = lane & 15, lk = lane >> 4;
  const unsigned short* e16 = (const unsigned short*)(ws + WS_E16);
  const unsigned short* f16 = (const unsigned short*)(ws + WS_F16);
  const unsigned short* bmp = (const unsigned short*)(ws + WS_BM);
  unsigned short* po = (unsigned short*)(ws + WS_PO);
  float* rs = ws + WS_RS;
  int n0 = nt*128, g0 = gt*128;
  if (t < 128) lL[t] = last_node[b*Gg + ((g0 + t) < Gg ? (g0 + t) : Gg-1)];
  __syncthreads();
  f32x4 acc[4][4] = {};
  int srow = t >> 1, sc0 = (t & 1) * 4;
  int nr = n0 + srow; if (nr > Nn-1) nr = Nn-1;
  size_t ebase = ((size_t)(b*Nn + nr)) * Hh;
  size_t fbase = ((size_t)(b*GP + g0 + srow)) * Hh;
  for (int st = 0; st < 4; ++st) {
    int k0 = st * 64;
#pragma unroll
    for (int i = 0; i < 4; ++i) {
      int cc = sc0 + i;
      int d = SW(srow, cc);
      *(short8*)&sE[d] = *(const short8*)(e16 + ebase + k0 + cc*8);
      *(short8*)&sF[d] = *(const short8*)(f16 + fbase + k0 + cc*8);
    }
    __syncthreads();
#pragma unroll
    for (int kk = 0; kk < 64; kk += 32) {
      f16x8 a[4], bb[4];
#pragma unroll
      for (int fm = 0; fm < 4; ++fm)
        a[fm] = *(const f16x8*)&sE[SW(wn*64 + fm*16 + l15, (kk>>3) + lk)];
#pragma unroll
      for (int fn = 0; fn < 4; ++fn)
        bb[fn] = *(const f16x8*)&sF[SW(wg*64 + fn*16 + l15, (kk>>3) + lk)];
#pragma unroll
      for (int fm = 0; fm < 4; ++fm)
#pragma unroll
        for (int fn = 0; fn < 4; ++fn)
          acc[fm][fn] = MFMAH(a[fm], bb[fn], acc[fm][fn]);
    }
    __syncthreads();
  }
  const float c2 = 0.70710678118654752f;
  float rsum[4] = {0.f, 0.f, 0.f, 0.f};
#pragma unroll
  for (int fn = 0; fn < 4; ++fn) {
    int gl = wg*64 + fn*16 + l15;
    int g = g0 + gl;
    if (g < Gg) {
      int L = lL[gl];
      const float* drow = dists + ((size_t)(b*Nn + L)) * Nn;
      const unsigned short* bmr = bmp + ((size_t)(b*GP + g)) * 64;
      unsigned short* prow = po + ((size_t)(b*Gg + g)) * 1024;
#pragma unroll
      for (int fm = 0; fm < 4; ++fm) {
        int n = n0 + wn*64 + fm*16 + lk*4;
        if (n < Nn) {
          float4 d4 = *(const float4*)(drow + n);
          unsigned cb = bmr[n >> 4];
          int bo = n & 15;
          float dd[4] = {d4.x, d4.y, d4.z, d4.w};
          unsigned short h4[4];
#pragma unroll
          for (int j = 0; j < 4; ++j) {
            // p = exp(10*tanh(s) - 10), exp2-domain, rcp-approx division
            float s = fmaf(acc[fm][fn][j], 0.0625f, -dd[j] * c2);
            float e = __expf(-2.0f * fabsf(s));
            float r = __builtin_amdgcn_rcpf(1.0f + e);
            float m = fmaf(-20.0f, e * r, 10.0f);   // = 10*tanh(|s|)
            float parg = copysignf(m, s) - 10.0f;
            float p = ((cb >> (bo + j)) & 1) ? 0.f : __expf(parg);
            rsum[fn] += p;
            h4[j] = f16b(p);
          }
          uint2 u = { (unsigned)h4[0] | ((unsigned)h4[1] << 16),
                      (unsigned)h4[2] | ((unsigned)h4[3] << 16) };
          *(uint2*)(prow + n) = u;
        }
      }
    }
  }
#pragma unroll
  for (int fn = 0; fn < 4; ++fn) {
    rsum[fn] += __shfl_xor(rsum[fn], 16);
    rsum[fn] += __shfl_xor(rsum[fn], 32);
    int g = g0 + wg*64 + fn*16 + l15;
    if (lk == 0 && g < Gg) atomicAdd(rs + b*GP + g, rsum[fn]);
  }
}

// ---------------- normalize (wide): out[g][n] = fp16 p * (1/rs): grid(15625) --
__global__ __launch_bounds__(256) void k_norm(const float* __restrict__ ws,
                                              float* __restrict__ out) {
  int idx = blockIdx.x * 256 + threadIdx.x;   // 8-elem index, total 4,000,000
  int bg = idx / 125;                         // b*Gg + g
  int n = (idx - bg * 125) * 8;
  int b = bg / Gg, g = bg - b * Gg;
  const unsigned short* po = (const unsigned short*)(ws + WS_PO);
  float inv = 1.0f / ws[WS_RS + b*GP + g];
  uint4 u = *(const uint4*)(po + (size_t)bg * 1024 + n);
  float* orow = out + (size_t)bg * Nn + n;
  float4 o0, o1;
  o0.x = __half2float(__ushort_as_half((unsigned short)(u.x & 0xFFFF))) * inv;
  o0.y = __half2float(__ushort_as_half((unsigned short)(u.x >> 16))) * inv;
  o0.z = __half2float(__ushort_as_half((unsigned short)(u.y & 0xFFFF))) * inv;
  o0.w = __half2float(__ushort_as_half((unsigned short)(u.y >> 16))) * inv;
  o1.x = __half2float(__ushort_as_half((unsigned short)(u.z & 0xFFFF))) * inv;
  o1.y = __half2float(__ushort_as_half((unsigned short)(u.z >> 16))) * inv;
  o1.z = __half2float(__ushort_as_half((unsigned short)(u.w & 0xFFFF))) * inv;
  o1.w = __half2float(__ushort_as_half((unsigned short)(u.w >> 16))) * inv;
  *(float4*)orow = o0;
  *(float4*)(orow + 4) = o1;
}

extern "C" void kernel_launch(void* const* d_in, const int* in_sizes, int n_in,
                              void* d_out, int out_size, void* d_ws, size_t ws_size,
                              hipStream_t stream) {
  const float* emb       = (const float*)d_in[0];
  const float* dists     = (const float*)d_in[1];
  const int*   last_node = (const int*)d_in[2];
  const float* gm        = (const float*)d_in[3];
  const float* Wg        = (const float*)d_in[4];
  const float* Wf        = (const float*)d_in[5];
  const float* Wl        = (const float*)d_in[6];
  const float* Wv        = (const float*)d_in[7];
  float* out = (float*)d_out;
  float* ws  = (float*)d_ws;

  hipLaunchKernelGGL(k_misc,   dim3(8576),      dim3(256), 0, stream, gm, Wf, Wl, Wv, ws);
  hipLaunchKernelGGL(k_prep,   dim3(16,4,Bb),   dim3(256), 0, stream, emb, ws);
  hipLaunchKernelGGL(k_qgraph, dim3(Bb),        dim3(256), 0, stream, Wg, ws);
  hipLaunchKernelGGL(k_pool,   dim3(2,4,Bb),    dim3(256), 0, stream, ws);
  hipLaunchKernelGGL(k_finalq, dim3(2,4,Bb),    dim3(256), 0, stream, last_node, ws);
  hipLaunchKernelGGL(k_score,  dim3(2048),      dim3(256), 0, stream, dists, last_node, ws);
  hipLaunchKernelGGL(k_norm,   dim3(15625),     dim3(256), 0, stream, ws, out);
}